// Round 6
// baseline (174.556 us; speedup 1.0000x reference)
//
#include <hip/hip_runtime.h>
#include <hip/hip_bf16.h>
#include <math.h>

// GeomAttention: B=2, L=S=2048, H=8, E=D=32, fp32 in/out.
// scores = (0.5*dot - 0.5*relu(qn2*kn2 - dot^2))/sqrt(E); softmax over S; out = attn@V.
// Round 6: zero-sync main loop, 4-way key split ACROSS blocks (2048 blocks x 256 thr =
// 32 waves/CU), pre-converted bf16 operands in ws, fp32 partials + combine kernel.
// Fallback (ws too small): round-4 kernel (validated, ~81us), distinct name for rocprof.

#define NB 2
#define NL 2048
#define NS 2048
#define NH 8
#define NBH 16
#define CSC 0.12751742f  // 0.5 / sqrt(32) * log2(e)

// ---- workspace layout (split4 path) ----
#define WS_KN2_OFF 0u
#define WS_KHKL_OFF 131072u                            // 16*2048 f32
#define WS_VT_OFF (131072u + 4194304u)                 // + 16*2048*64 u16
#define WS_PACC_OFF (131072u + 4194304u + 2097152u)    // + 16*32*2048 u16
#define WS_PML_OFF (WS_PACC_OFF + 16777216u)           // + 16*4*2048*32 f32
#define WS_NEED (WS_PML_OFF + 1048576u)                // + 16*4*2048*2 f32 = 24,248,320 B

typedef float f32x4 __attribute__((ext_vector_type(4)));
typedef short s16x8 __attribute__((ext_vector_type(8)));
typedef unsigned short u16;

__device__ inline unsigned pk2(float a, float b) {  // bf16(a)|bf16(b)<<16, RNE
    __hip_bfloat162 t = __float22bfloat162_rn(make_float2(a, b));
    union { __hip_bfloat162 h; unsigned u; } cv;
    cv.h = t;
    return cv.u;
}
template <int CTRL>
__device__ inline float dpp_add(float x) {
    return x + __int_as_float(__builtin_amdgcn_mov_dpp(__float_as_int(x), CTRL, 0xF, 0xF, false));
}
// swizzles for fallback kernel (chunk = 8 u16 = 16 B)
__device__ inline int swzK(int row) { return (row ^ (row >> 2)) & 3; }
__device__ inline int swzV(int row) { return (row + (row >> 3)) & 7; }
__device__ inline int swzP(int row) { return row & 7; }

// ==== pre-kernel: K -> bf16 hi/lo [bh][s][2][32], V -> bf16 V^T [bh][d][s], kn2 fp32 ====
__global__ __launch_bounds__(256) void ga_pre(const float* __restrict__ K,
                                              const float* __restrict__ V,
                                              float* __restrict__ kn2w,
                                              u16* __restrict__ khkl,
                                              u16* __restrict__ vtw) {
    __shared__ float Vf[64][36];
    const int T = threadIdx.x;
    const int bh = blockIdx.x >> 5, stile = blockIdx.x & 31;
    const int b = bh >> 3, h = bh & 7;
    const int s0 = stile * 64;
    const int sk = T >> 2, kc = (T & 3) * 8;

    const float* kp = K + ((size_t)((b * NS + s0 + sk) * NH + h)) * 32 + kc;
    float4 f0 = *(const float4*)kp, f1 = *(const float4*)(kp + 4);
    float kx[8] = {f0.x, f0.y, f0.z, f0.w, f1.x, f1.y, f1.z, f1.w};
    unsigned hh[4], ll[4];
    float kn2p = 0.f;
#pragma unroll
    for (int i = 0; i < 4; i++) {
        float x0 = kx[2 * i], x1 = kx[2 * i + 1];
        kn2p = fmaf(x0, x0, kn2p);
        kn2p = fmaf(x1, x1, kn2p);
        unsigned h01 = pk2(x0, x1);
        hh[i] = h01;
        float h0 = __uint_as_float(h01 << 16);
        float h1 = __uint_as_float(h01 & 0xffff0000u);
        ll[i] = pk2(x0 - h0, x1 - h1);
    }
    u16* kd = khkl + ((size_t)(bh * NS + s0 + sk)) * 64 + kc;
    *(uint4*)kd = make_uint4(hh[0], hh[1], hh[2], hh[3]);
    *(uint4*)(kd + 32) = make_uint4(ll[0], ll[1], ll[2], ll[3]);
    kn2p = dpp_add<0xB1>(kn2p);
    kn2p = dpp_add<0x4E>(kn2p);
    if ((T & 3) == 0) kn2w[bh * NS + s0 + sk] = kn2p;

    const float* vp = V + ((size_t)((b * NS + s0 + sk) * NH + h)) * 32 + kc;
    float4 g0 = *(const float4*)vp, g1 = *(const float4*)(vp + 4);
    *(float4*)&Vf[sk][kc] = g0;
    *(float4*)&Vf[sk][kc + 4] = g1;
    __syncthreads();
    const int dr = T >> 3, sc8 = (T & 7) * 8;
    float vv[8];
#pragma unroll
    for (int i = 0; i < 8; i++) vv[i] = Vf[sc8 + i][dr];
    *(uint4*)(vtw + ((size_t)(bh * 32 + dr)) * NS + s0 + sc8) =
        make_uint4(pk2(vv[0], vv[1]), pk2(vv[2], vv[3]), pk2(vv[4], vv[5]), pk2(vv[6], vv[7]));
}

// ==== main kernel: 2048 blocks x 256 thr, no __syncthreads anywhere ====
__global__ __launch_bounds__(256, 6) void ga_split4(
    const float* __restrict__ Q, const float* __restrict__ kn2w,
    const u16* __restrict__ khkl, const u16* __restrict__ vtw,
    float* __restrict__ pacc, float* __restrict__ pml) {
    __shared__ u16 sP[4][16][64];  // per-wave P^T round-trip, chunk-XOR swizzled

    const int T = threadIdx.x;
    const int lane = T & 63, wave = T >> 6;
    const int g = lane >> 4, lc = lane & 15, g8 = g * 8;
    const int blk = blockIdx.x;
    const int qt = blk & 31, strip = (blk >> 5) & 3, bh = blk >> 7;
    const int b = bh >> 3, h = bh & 7;
    const int qw = qt * 64 + wave * 16;
    const int kb0 = strip * 512;

    // ---- Q fragments (B-operand; hi/lo bf16) + exact qn2, in-lane ----
    const float* qrow = Q + ((size_t)((b * NL + qw + lc) * NH + h)) * 32 + g8;
    float4 qa = *(const float4*)qrow, qb = *(const float4*)(qrow + 4);
    float q8[8] = {qa.x, qa.y, qa.z, qa.w, qb.x, qb.y, qb.z, qb.w};
    union { unsigned u4[4]; s16x8 v; } qh_, ql_;
    float qn2 = 0.f;
#pragma unroll
    for (int i = 0; i < 4; i++) {
        float x0 = q8[2 * i], x1 = q8[2 * i + 1];
        qn2 = fmaf(x0, x0, qn2);
        qn2 = fmaf(x1, x1, qn2);
        unsigned h01 = pk2(x0, x1);
        qh_.u4[i] = h01;
        float h0 = __uint_as_float(h01 << 16);
        float h1 = __uint_as_float(h01 & 0xffff0000u);
        ql_.u4[i] = pk2(x0 - h0, x1 - h1);
    }
    const s16x8 qh = qh_.v, ql = ql_.v;
    qn2 += __shfl_xor(qn2, 16);
    qn2 += __shfl_xor(qn2, 32);  // qn2 of query lc in every lane

    const float* kn2b = kn2w + (size_t)bh * NS + kb0;
    const u16* khb = khkl + ((size_t)(bh * NS + kb0)) * 64;
    const u16* vtb = vtw + ((size_t)bh * 32) * NS + kb0;

    s16x8 ones;
#pragma unroll
    for (int i = 0; i < 8; i++) ones[i] = (short)0x3F80;  // bf16 1.0

    f32x4 acc0 = {0.f, 0.f, 0.f, 0.f}, acc1 = {0.f, 0.f, 0.f, 0.f};
    float m = -1e30f, l = 0.f;
    const f32x4 z = {0.f, 0.f, 0.f, 0.f};

    for (int t = 0; t < 8; ++t) {
        const int kl64 = t * 64;
        // ---- operand fragments from pre-converted global (b128, block-shared -> L1) ----
        s16x8 kh[4], klo[4], va[4];
        f32x4 kn2v[4];
#pragma unroll
        for (int st = 0; st < 4; st++) {
            const u16* kp = khb + (size_t)(kl64 + 16 * st + lc) * 64 + g8;
            kh[st] = *(const s16x8*)kp;
            klo[st] = *(const s16x8*)(kp + 32);
        }
        va[0] = *(const s16x8*)(vtb + (size_t)lc * NS + kl64 + g8);
        va[1] = *(const s16x8*)(vtb + (size_t)lc * NS + kl64 + 32 + g8);
        va[2] = *(const s16x8*)(vtb + (size_t)(lc + 16) * NS + kl64 + g8);
        va[3] = *(const s16x8*)(vtb + (size_t)(lc + 16) * NS + kl64 + 32 + g8);
#pragma unroll
        for (int st = 0; st < 4; st++)
            kn2v[st] = *(const f32x4*)(kn2b + kl64 + 16 * st + 4 * g);

        // ---- S^T = K·Q^T: 3-MFMA hi/lo per 16-key subtile ----
        f32x4 d[4];
#pragma unroll
        for (int st = 0; st < 4; st++) {
            f32x4 dd = __builtin_amdgcn_mfma_f32_16x16x32_bf16(klo[st], qh, z, 0, 0, 0);
            dd = __builtin_amdgcn_mfma_f32_16x16x32_bf16(kh[st], ql, dd, 0, 0, 0);
            dd = __builtin_amdgcn_mfma_f32_16x16x32_bf16(kh[st], qh, dd, 0, 0, 0);
            d[st] = dd;  // C[key=16st+4g+r][query=lc]
        }

        // ---- scores: sc = min(d, d + (d^2 - qn2*kn2)) (pre-CSC log2 domain) ----
        float sc[4][4];
#pragma unroll
        for (int st = 0; st < 4; st++)
#pragma unroll
            for (int r = 0; r < 4; r++) {
                float dd = d[st][r];
                float c = qn2 * kn2v[st][r];
                sc[st][r] = fminf(dd, fmaf(dd, dd, -c) + dd);
            }

        // ---- online softmax ----
        float x0 = fmaxf(fmaxf(sc[0][0], sc[0][1]), fmaxf(sc[0][2], sc[0][3]));
        float x1 = fmaxf(fmaxf(sc[1][0], sc[1][1]), fmaxf(sc[1][2], sc[1][3]));
        float x2 = fmaxf(fmaxf(sc[2][0], sc[2][1]), fmaxf(sc[2][2], sc[2][3]));
        float x3 = fmaxf(fmaxf(sc[3][0], sc[3][1]), fmaxf(sc[3][2], sc[3][3]));
        float tm = fmaxf(fmaxf(x0, x1), fmaxf(x2, x3));
        tm = fmaxf(tm, __shfl_xor(tm, 16));
        tm = fmaxf(tm, __shfl_xor(tm, 32));
        const float nm = fmaxf(m, tm);
        const float negmC = -nm * CSC;
        const float al = __builtin_amdgcn_exp2f(fmaf(m, CSC, negmC));
        m = nm;
        float p[4][4];
#pragma unroll
        for (int st = 0; st < 4; st++)
#pragma unroll
            for (int r = 0; r < 4; r++)
                p[st][r] = __builtin_amdgcn_exp2f(fmaf(sc[st][r], CSC, negmC));

        // ---- P^T -> per-wave LDS (swizzled, conflict-free), own-wave round-trip ----
#pragma unroll
        for (int st = 0; st < 4; st++) {
            const int off = (((2 * st + (g >> 1)) ^ (lc & 7)) << 3) + ((g & 1) << 2);
            *(uint2*)&sP[wave][lc][off] =
                make_uint2(pk2(p[st][0], p[st][1]), pk2(p[st][2], p[st][3]));
        }
        __builtin_amdgcn_s_waitcnt(0xC07F);  // lgkmcnt(0)
        s16x8 pb0 = *(s16x8*)&sP[wave][lc][(g ^ (lc & 7)) << 3];
        s16x8 pb1 = *(s16x8*)&sP[wave][lc][((4 + g) ^ (lc & 7)) << 3];

        // ---- rescale + PV + l via ones-MFMA ----
        acc0 *= al;
        acc1 *= al;
        acc0 = __builtin_amdgcn_mfma_f32_16x16x32_bf16(va[0], pb0, acc0, 0, 0, 0);
        acc0 = __builtin_amdgcn_mfma_f32_16x16x32_bf16(va[1], pb1, acc0, 0, 0, 0);
        acc1 = __builtin_amdgcn_mfma_f32_16x16x32_bf16(va[2], pb0, acc1, 0, 0, 0);
        acc1 = __builtin_amdgcn_mfma_f32_16x16x32_bf16(va[3], pb1, acc1, 0, 0, 0);
        f32x4 lt = __builtin_amdgcn_mfma_f32_16x16x32_bf16(ones, pb0, z, 0, 0, 0);
        lt = __builtin_amdgcn_mfma_f32_16x16x32_bf16(ones, pb1, lt, 0, 0, 0);
        l = fmaf(l, al, lt[0]);
    }

    // ---- write fp32 partials (no block sync needed) ----
    float* pa = pacc + (((size_t)bh * 4 + strip) * NL + (qw + lc)) * 32;
    *(f32x4*)(pa + 4 * g) = acc0;        // O^T rows d=4g+r
    *(f32x4*)(pa + 16 + 4 * g) = acc1;   // d=16+4g+r
    if (g == 0) {
        float2 ml = make_float2(m, l);
        *(float2*)(pml + (((size_t)bh * 4 + strip) * NL + (qw + lc)) * 2) = ml;
    }
}

// ==== combine kernel: merge 4 strips per (bh,q) ====
__global__ __launch_bounds__(256) void ga_combine(const float* __restrict__ pacc,
                                                  const float* __restrict__ pml,
                                                  float* __restrict__ O) {
    const int tid = blockIdx.x * 256 + threadIdx.x;
    const int dq = tid & 7, q = (tid >> 3) & 2047, bh = tid >> 14;
    const int b = bh >> 3, h = bh & 7;
    float m[4], l[4];
#pragma unroll
    for (int s = 0; s < 4; s++) {
        float2 t = *(const float2*)(pml + (((size_t)bh * 4 + s) * NL + q) * 2);
        m[s] = t.x;
        l[s] = t.y;
    }
    float mf = fmaxf(fmaxf(m[0], m[1]), fmaxf(m[2], m[3]));
    float w[4], L = 0.f;
#pragma unroll
    for (int s = 0; s < 4; s++) {
        w[s] = __builtin_amdgcn_exp2f((m[s] - mf) * CSC);
        L = fmaf(l[s], w[s], L);
    }
    const float inv = 1.f / L;
    float4 o = make_float4(0.f, 0.f, 0.f, 0.f);
#pragma unroll
    for (int s = 0; s < 4; s++) {
        const float* pa = pacc + (((size_t)bh * 4 + s) * NL + q) * 32 + dq * 4;
        float4 a = *(const float4*)pa;
        o.x = fmaf(a.x, w[s], o.x);
        o.y = fmaf(a.y, w[s], o.y);
        o.z = fmaf(a.z, w[s], o.z);
        o.w = fmaf(a.w, w[s], o.w);
    }
    o.x *= inv; o.y *= inv; o.z *= inv; o.w *= inv;
    *(float4*)(O + (((size_t)(b * NL + q)) * NH + h) * 32 + dq * 4) = o;
}

// ==== fallback: round-4 kernel verbatim (validated ~81us), no workspace ====
__global__ __launch_bounds__(512, 4) void ga_fallback(
    const float* __restrict__ Q, const float* __restrict__ K,
    const float* __restrict__ V, float* __restrict__ O) {
    __shared__ union {
        struct {
            u16 Kh[2][64][32];
            u16 Kl[2][64][32];
            u16 Vt[2][32][64];
            float kn2[2][64];
        } s;
        struct { float acc[8][32][17]; float m[8][16]; float l[8][16]; } c;
    } u;
    __shared__ u16 sP[8][16][64];

    const int T = threadIdx.x;
    const int lane = T & 63, wave = T >> 6;
    const int g = lane >> 4, lc = lane & 15, g8 = g * 8;
    const int half = wave >> 2;
    const int qt = blockIdx.x & 31;
    const int bh = blockIdx.x >> 5;
    const int b = bh >> 3, h = bh & 7;
    const int qw = qt * 64 + (wave & 3) * 16;

    const float* qrow = Q + ((size_t)((b * NL + qw + lc) * NH + h)) * 32 + g8;
    float4 qa = *(const float4*)qrow, qb = *(const float4*)(qrow + 4);
    float q8[8] = {qa.x, qa.y, qa.z, qa.w, qb.x, qb.y, qb.z, qb.w};
    union { unsigned u4[4]; s16x8 v; } qh_, ql_;
    float qn2 = 0.f;
#pragma unroll
    for (int i = 0; i < 4; i++) {
        float x0 = q8[2 * i], x1 = q8[2 * i + 1];
        qn2 = fmaf(x0, x0, qn2);
        qn2 = fmaf(x1, x1, qn2);
        unsigned h01 = pk2(x0, x1);
        qh_.u4[i] = h01;
        float h0 = __uint_as_float(h01 << 16);
        float h1 = __uint_as_float(h01 & 0xffff0000u);
        ql_.u4[i] = pk2(x0 - h0, x1 - h1);
    }
    const s16x8 qh = qh_.v, ql = ql_.v;
    qn2 += __shfl_xor(qn2, 16);
    qn2 += __shfl_xor(qn2, 32);

    const int Tl = T & 255;
    const int sk = Tl >> 2, kc = Tl & 3;
    const int dv = Tl & 31, vc = Tl >> 5;
    const float* kbase = K + ((size_t)(b * NS * NH) + h) * 32;
    const float* vbase = V + ((size_t)(b * NS * NH) + h) * 32;
    const int kphys = (kc ^ swzK(sk)) * 8;
    const int vphys = (vc ^ swzV(dv)) * 8;

    int s0 = half * 1024;
    float4 ka = *(const float4*)(kbase + (size_t)(s0 + sk) * 256 + kc * 8);
    float4 kb = *(const float4*)(kbase + (size_t)(s0 + sk) * 256 + kc * 8 + 4);
    float vr[8];
#pragma unroll
    for (int i = 0; i < 8; i++) vr[i] = vbase[(size_t)(s0 + 8 * vc + i) * 256 + dv];

    f32x4 acc0 = {0.f, 0.f, 0.f, 0.f}, acc1 = {0.f, 0.f, 0.f, 0.f};
    float m = -INFINITY, l = 0.f;

    for (int t = 0; t < 16; ++t) {
        {
            float kx[8] = {ka.x, ka.y, ka.z, ka.w, kb.x, kb.y, kb.z, kb.w};
            unsigned hh[4], ll[4];
            float kn2p = 0.f;
#pragma unroll
            for (int i = 0; i < 4; i++) {
                float x0 = kx[2 * i], x1 = kx[2 * i + 1];
                kn2p = fmaf(x0, x0, kn2p);
                kn2p = fmaf(x1, x1, kn2p);
                unsigned h01 = pk2(x0, x1);
                hh[i] = h01;
                float h0 = __uint_as_float(h01 << 16);
                float h1 = __uint_as_float(h01 & 0xffff0000u);
                ll[i] = pk2(x0 - h0, x1 - h1);
            }
            *(uint4*)&u.s.Kh[half][sk][kphys] = make_uint4(hh[0], hh[1], hh[2], hh[3]);
            *(uint4*)&u.s.Kl[half][sk][kphys] = make_uint4(ll[0], ll[1], ll[2], ll[3]);
            kn2p = dpp_add<0xB1>(kn2p);
            kn2p = dpp_add<0x4E>(kn2p);
            if (kc == 0) u.s.kn2[half][sk] = kn2p;
            *(uint4*)&u.s.Vt[half][dv][vphys] =
                make_uint4(pk2(vr[0], vr[1]), pk2(vr[2], vr[3]),
                           pk2(vr[4], vr[5]), pk2(vr[6], vr[7]));
        }
        const int tn = (t + 1 < 16) ? t + 1 : t;
        const int sn = half * 1024 + tn * 64;
        ka = *(const float4*)(kbase + (size_t)(sn + sk) * 256 + kc * 8);
        kb = *(const float4*)(kbase + (size_t)(sn + sk) * 256 + kc * 8 + 4);
#pragma unroll
        for (int i = 0; i < 8; i++) vr[i] = vbase[(size_t)(sn + 8 * vc + i) * 256 + dv];

        __syncthreads();

        f32x4 d[4], kn2v[4];
        const f32x4 z = {0.f, 0.f, 0.f, 0.f};
        const int skr = swzK(lc);
#pragma unroll
        for (int st = 0; st < 4; st++) {
            kn2v[st] = *(f32x4*)&u.s.kn2[half][16 * st + 4 * g];
            s16x8 kh = *(s16x8*)&u.s.Kh[half][16 * st + lc][(g ^ skr) * 8];
            s16x8 kl = *(s16x8*)&u.s.Kl[half][16 * st + lc][(g ^ skr) * 8];
            f32x4 dd = __builtin_amdgcn_mfma_f32_16x16x32_bf16(kl, qh, z, 0, 0, 0);
            dd = __builtin_amdgcn_mfma_f32_16x16x32_bf16(kh, ql, dd, 0, 0, 0);
            dd = __builtin_amdgcn_mfma_f32_16x16x32_bf16(kh, qh, dd, 0, 0, 0);
            d[st] = dd;
        }

        float sc[4][4];
#pragma unroll
        for (int st = 0; st < 4; st++)
#pragma unroll
            for (int r = 0; r < 4; r++) {
                float dd = d[st][r];
                float w = fmaxf(fmaf(-dd, dd, qn2 * kn2v[st][r]), 0.f);
                sc[st][r] = (dd - w) * CSC;
            }

        float x0 = fmaxf(fmaxf(sc[0][0], sc[0][1]), fmaxf(sc[0][2], sc[0][3]));
        float x1 = fmaxf(fmaxf(sc[1][0], sc[1][1]), fmaxf(sc[1][2], sc[1][3]));
        float x2 = fmaxf(fmaxf(sc[2][0], sc[2][1]), fmaxf(sc[2][2], sc[2][3]));
        float x3 = fmaxf(fmaxf(sc[3][0], sc[3][1]), fmaxf(sc[3][2], sc[3][3]));
        float tm = fmaxf(fmaxf(x0, x1), fmaxf(x2, x3));
        tm = fmaxf(tm, __shfl_xor(tm, 16));
        tm = fmaxf(tm, __shfl_xor(tm, 32));
        const float nm = fmaxf(m, tm);
        const float al = __builtin_amdgcn_exp2f(m - nm);
        m = nm;
        float p[4][4], ls = 0.f;
#pragma unroll
        for (int st = 0; st < 4; st++)
#pragma unroll
            for (int r = 0; r < 4; r++) {
                p[st][r] = __builtin_amdgcn_exp2f(sc[st][r] - nm);
                ls += p[st][r];
            }
        l = fmaf(l, al, ls);
        acc0 *= al;
        acc1 *= al;

#pragma unroll
        for (int st = 0; st < 4; st++) {
            const int chunkl = 2 * st + (g >> 1);
            const int off = (chunkl ^ swzP(lc)) * 8 + (g & 1) * 4;
            *(uint2*)&sP[wave][lc][off] =
                make_uint2(pk2(p[st][0], p[st][1]), pk2(p[st][2], p[st][3]));
        }
        __builtin_amdgcn_s_waitcnt(0xC07F);

        const int svl = swzV(lc), svh = swzV(lc + 16), spl = swzP(lc);
        s16x8 va00 = *(s16x8*)&u.s.Vt[half][lc][(g ^ svl) * 8];
        s16x8 va01 = *(s16x8*)&u.s.Vt[half][lc][((4 + g) ^ svl) * 8];
        s16x8 va10 = *(s16x8*)&u.s.Vt[half][lc + 16][(g ^ svh) * 8];
        s16x8 va11 = *(s16x8*)&u.s.Vt[half][lc + 16][((4 + g) ^ svh) * 8];
        s16x8 pb0 = *(s16x8*)&sP[wave][lc][(g ^ spl) * 8];
        s16x8 pb1 = *(s16x8*)&sP[wave][lc][((4 + g) ^ spl) * 8];
        acc0 = __builtin_amdgcn_mfma_f32_16x16x32_bf16(va00, pb0, acc0, 0, 0, 0);
        acc0 = __builtin_amdgcn_mfma_f32_16x16x32_bf16(va01, pb1, acc0, 0, 0, 0);
        acc1 = __builtin_amdgcn_mfma_f32_16x16x32_bf16(va10, pb0, acc1, 0, 0, 0);
        acc1 = __builtin_amdgcn_mfma_f32_16x16x32_bf16(va11, pb1, acc1, 0, 0, 0);

        __syncthreads();
    }

    l += __shfl_xor(l, 16);
    l += __shfl_xor(l, 32);
#pragma unroll
    for (int r = 0; r < 4; r++) {
        u.c.acc[wave][4 * g + r][lc] = acc0[r];
        u.c.acc[wave][16 + 4 * g + r][lc] = acc1[r];
    }
    if (lane < 16) {
        u.c.m[wave][lc] = m;
        u.c.l[wave][lc] = l;
    }
    __syncthreads();

    const int q = T >> 3, dq = (T & 7) * 4, qr = q & 15;
    const int w0 = q >> 4, w1 = w0 + 4;
    float m0 = u.c.m[w0][qr], m1 = u.c.m[w1][qr];
    float l0 = u.c.l[w0][qr], l1 = u.c.l[w1][qr];
    float mf = fmaxf(m0, m1);
    float e0 = __builtin_amdgcn_exp2f(m0 - mf);
    float e1 = __builtin_amdgcn_exp2f(m1 - mf);
    float inv = 1.f / fmaf(l1, e1, l0 * e0);
    e0 *= inv;
    e1 *= inv;
    float4 o;
    o.x = u.c.acc[w0][dq + 0][qr] * e0 + u.c.acc[w1][dq + 0][qr] * e1;
    o.y = u.c.acc[w0][dq + 1][qr] * e0 + u.c.acc[w1][dq + 1][qr] * e1;
    o.z = u.c.acc[w0][dq + 2][qr] * e0 + u.c.acc[w1][dq + 2][qr] * e1;
    o.w = u.c.acc[w0][dq + 3][qr] * e0 + u.c.acc[w1][dq + 3][qr] * e1;
    *(float4*)(O + ((size_t)((b * NL + qt * 64 + q) * NH + h)) * 32 + dq) = o;
}

extern "C" void kernel_launch(void* const* d_in, const int* in_sizes, int n_in,
                              void* d_out, int out_size, void* d_ws, size_t ws_size,
                              hipStream_t stream) {
    const float* Q = (const float*)d_in[0];
    const float* K = (const float*)d_in[1];
    const float* V = (const float*)d_in[2];
    float* O = (float*)d_out;

    if (ws_size >= (size_t)WS_NEED) {
        float* kn2w = (float*)((char*)d_ws + WS_KN2_OFF);
        u16* khkl = (u16*)((char*)d_ws + WS_KHKL_OFF);
        u16* vtw = (u16*)((char*)d_ws + WS_VT_OFF);
        float* pacc = (float*)((char*)d_ws + WS_PACC_OFF);
        float* pml = (float*)((char*)d_ws + WS_PML_OFF);
        ga_pre<<<NBH * 32, 256, 0, stream>>>(K, V, kn2w, khkl, vtw);
        ga_split4<<<NBH * 32 * 4, 256, 0, stream>>>(Q, kn2w, khkl, vtw, pacc, pml);
        ga_combine<<<(NBH * NL * 8) / 256, 256, 0, stream>>>(pacc, pml, O);
    } else {
        ga_fallback<<<NBH * 32, 512, 0, stream>>>(Q, K, V, O);
    }
}

// Round 7
// 105.683 us; speedup vs baseline: 1.6517x; 1.6517x over previous
//
#include <hip/hip_runtime.h>
#include <hip/hip_bf16.h>
#include <math.h>

// GeomAttention: B=2, L=S=2048, H=8, E=D=32, fp32 in/out.
// scores = (0.5*dot - 0.5*relu(qn2*kn2 - dot^2))/sqrt(E); softmax over S; out = attn@V.
// Round 7: pre-kernel writes bank-swizzled LDS-image operands (K hi/lo, V^T) to ws;
// main kernel stages via global_load_lds dwordx4 (coalesced DMA, double-buffered),
// reads fragments from LDS (swizzle => <=2-way banks, free), one barrier/tile,
// 2048 small blocks (4 waves) so blocks interleave across barriers. Partials+combine.

#define NB 2
#define NL 2048
#define NS 2048
#define NH 8
#define NBH 16
#define CSC 0.12751742f  // 0.5 / sqrt(32) * log2(e)

#define WS_KN2_OFF 0u
#define WS_KHKL_OFF 131072u                          // 16*2048 f32
#define WS_VT_OFF (131072u + 4194304u)               // + 16*2048*128B (K hi/lo image)
#define WS_PACC_OFF (131072u + 4194304u + 2097152u)  // + 16*32*2048*2B (V^T image)
#define WS_PML_OFF (WS_PACC_OFF + 16777216u)         // + 16*4*2048*32 f32
#define WS_NEED (WS_PML_OFF + 1048576u)              // + 16*4*2048*2 f32 = 24,248,320 B

typedef float f32x4 __attribute__((ext_vector_type(4)));
typedef short s16x8 __attribute__((ext_vector_type(8)));
typedef unsigned short u16;

__device__ inline unsigned pk2(float a, float b) {  // bf16(a)|bf16(b)<<16, RNE
    __hip_bfloat162 t = __float22bfloat162_rn(make_float2(a, b));
    union { __hip_bfloat162 h; unsigned u; } cv;
    cv.h = t;
    return cv.u;
}
template <int CTRL>
__device__ inline float dpp_add(float x) {
    return x + __int_as_float(__builtin_amdgcn_mov_dpp(__float_as_int(x), CTRL, 0xF, 0xF, false));
}
// async global->LDS DMA, 16 B/lane; LDS dest = uniform base + lane*16 [m97/m104]
__device__ inline void dma16(const void* gp, void* lp) {
    __builtin_amdgcn_global_load_lds(
        (__attribute__((address_space(1))) void*)(void*)gp,
        (__attribute__((address_space(3))) void*)lp, 16, 0, 0);
}
// fallback-kernel swizzles
__device__ inline int swzK(int row) { return (row ^ (row >> 2)) & 3; }
__device__ inline int swzV(int row) { return (row + (row >> 3)) & 7; }

// ==== pre-kernel: swizzled LDS-image layouts ====
// K image: [bh][key][8 chunks x 16B], phys = logical ^ (key&7); logical 0-3 = hi, 4-7 = lo.
// V image: [bh][d][s], per-64-key tile 8 chunks, phys = logical ^ (d&7). kn2 exact fp32.
__global__ __launch_bounds__(256) void ga_pre(const float* __restrict__ K,
                                              const float* __restrict__ V,
                                              float* __restrict__ kn2w,
                                              u16* __restrict__ khkl,
                                              u16* __restrict__ vtw) {
    __shared__ float Vf[64][36];
    const int T = threadIdx.x;
    const int bh = blockIdx.x >> 5, stile = blockIdx.x & 31;
    const int b = bh >> 3, h = bh & 7;
    const int s0 = stile * 64;
    const int sk = T >> 2, kc = T & 3;

    const float* kp = K + ((size_t)((b * NS + s0 + sk) * NH + h)) * 32 + kc * 8;
    float4 f0 = *(const float4*)kp, f1 = *(const float4*)(kp + 4);
    float kx[8] = {f0.x, f0.y, f0.z, f0.w, f1.x, f1.y, f1.z, f1.w};
    unsigned hh[4], ll[4];
    float kn2p = 0.f;
#pragma unroll
    for (int i = 0; i < 4; i++) {
        float x0 = kx[2 * i], x1 = kx[2 * i + 1];
        kn2p = fmaf(x0, x0, kn2p);
        kn2p = fmaf(x1, x1, kn2p);
        unsigned h01 = pk2(x0, x1);
        hh[i] = h01;
        float h0 = __uint_as_float(h01 << 16);
        float h1 = __uint_as_float(h01 & 0xffff0000u);
        ll[i] = pk2(x0 - h0, x1 - h1);
    }
    u16* kd = khkl + ((size_t)(bh * NS + s0 + sk)) * 64;
    const int swk = sk & 7;
    *(uint4*)(kd + ((kc ^ swk) * 8)) = make_uint4(hh[0], hh[1], hh[2], hh[3]);
    *(uint4*)(kd + (((4 + kc) ^ swk) * 8)) = make_uint4(ll[0], ll[1], ll[2], ll[3]);
    kn2p = dpp_add<0xB1>(kn2p);
    kn2p = dpp_add<0x4E>(kn2p);
    if (kc == 0) kn2w[bh * NS + s0 + sk] = kn2p;

    const float* vp = V + ((size_t)((b * NS + s0 + sk) * NH + h)) * 32 + kc * 8;
    float4 g0 = *(const float4*)vp, g1 = *(const float4*)(vp + 4);
    *(float4*)&Vf[sk][kc * 8] = g0;
    *(float4*)&Vf[sk][kc * 8 + 4] = g1;
    __syncthreads();
    const int dr = T >> 3, c = T & 7;
    float vv[8];
#pragma unroll
    for (int i = 0; i < 8; i++) vv[i] = Vf[c * 8 + i][dr];
    const int phys = c ^ (dr & 7);
    *(uint4*)(vtw + ((size_t)(bh * 32 + dr)) * NS + s0 + phys * 8) =
        make_uint4(pk2(vv[0], vv[1]), pk2(vv[2], vv[3]), pk2(vv[4], vv[5]), pk2(vv[6], vv[7]));
}

// ==== main kernel: DMA-staged, double-buffered, one barrier per tile ====
__global__ __launch_bounds__(256, 4) void ga_dma(
    const float* __restrict__ Q, const float* __restrict__ kn2w,
    const u16* __restrict__ khkl, const u16* __restrict__ vtw,
    float* __restrict__ pacc, float* __restrict__ pml) {
    __shared__ u16 sK[2][64][64];  // [buf][key][8 phys chunks x 8 u16]  16 KB
    __shared__ u16 sV[2][32][64];  // [buf][d][8 phys chunks]             8 KB
    __shared__ u16 sP[4][16][64];  // per-wave P^T round-trip             8 KB

    const int T = threadIdx.x;
    const int lane = T & 63, wave = T >> 6;
    const int g = lane >> 4, lc = lane & 15, g8 = g * 8;
    const int blk = blockIdx.x;
    const int qt = blk & 31, strip = (blk >> 5) & 3, bh = blk >> 7;
    const int b = bh >> 3, h = bh & 7;
    const int qw = qt * 64 + wave * 16;
    const int kb0 = strip * 512;

    // ---- Q fragments (hi/lo bf16) + exact qn2, in-lane ----
    const float* qrow = Q + ((size_t)((b * NL + qw + lc) * NH + h)) * 32 + g8;
    float4 qa = *(const float4*)qrow, qb = *(const float4*)(qrow + 4);
    float q8[8] = {qa.x, qa.y, qa.z, qa.w, qb.x, qb.y, qb.z, qb.w};
    union { unsigned u4[4]; s16x8 v; } qh_, ql_;
    float qn2 = 0.f;
#pragma unroll
    for (int i = 0; i < 4; i++) {
        float x0 = q8[2 * i], x1 = q8[2 * i + 1];
        qn2 = fmaf(x0, x0, qn2);
        qn2 = fmaf(x1, x1, qn2);
        unsigned h01 = pk2(x0, x1);
        qh_.u4[i] = h01;
        float h0 = __uint_as_float(h01 << 16);
        float h1 = __uint_as_float(h01 & 0xffff0000u);
        ql_.u4[i] = pk2(x0 - h0, x1 - h1);
    }
    const s16x8 qh = qh_.v, ql = ql_.v;
    qn2 += __shfl_xor(qn2, 16);
    qn2 += __shfl_xor(qn2, 32);

    // ---- DMA source pointers (coalesced; ws layout == LDS image) ----
    const char* ksrc = (const char*)khkl +
        ((size_t)(bh * NS + kb0 + 16 * wave)) * 128 + lane * 16;
    const char* vsrc = (const char*)vtw +
        ((size_t)(bh * 32 + 8 * wave + (lane >> 3))) * (NS * 2) +
        (size_t)(kb0 + (lane & 7) * 8) * 2;
    const float* kn2b = kn2w + (size_t)bh * NS + kb0;

    // ---- prologue: stage tile 0 into buf 0 ----
    dma16(ksrc, &sK[0][16 * wave][0]);
    dma16(ksrc + 1024, &sK[0][16 * wave + 8][0]);
    dma16(vsrc, &sV[0][8 * wave][0]);
    __syncthreads();  // drains vmcnt -> tile 0 in LDS

    s16x8 ones;
#pragma unroll
    for (int i = 0; i < 8; i++) ones[i] = (short)0x3F80;  // bf16 1.0

    f32x4 acc0 = {0.f, 0.f, 0.f, 0.f}, acc1 = {0.f, 0.f, 0.f, 0.f};
    float m = -1e30f, l = 0.f;
    const f32x4 z = {0.f, 0.f, 0.f, 0.f};
    const int sw = lc & 7;

    for (int t = 0; t < 8; ++t) {
        const int cur = t & 1;
        // ---- issue DMA for tile t+1 into the other buffer (overlaps compute) ----
        if (t + 1 < 8) {
            const char* k2 = ksrc + (size_t)(t + 1) * 8192;
            const char* v2 = vsrc + (size_t)(t + 1) * 128;
            dma16(k2, &sK[cur ^ 1][16 * wave][0]);
            dma16(k2 + 1024, &sK[cur ^ 1][16 * wave + 8][0]);
            dma16(v2, &sV[cur ^ 1][8 * wave][0]);
        }
        const int kl64 = t * 64;

        // ---- QK^T from LDS fragments (swizzled reads: <=2-way banks) ----
        f32x4 d[4], kn2v[4];
#pragma unroll
        for (int st = 0; st < 4; st++) {
            kn2v[st] = *(const f32x4*)(kn2b + kl64 + 16 * st + 4 * g);
            s16x8 kh = *(s16x8*)&sK[cur][16 * st + lc][(g ^ sw) * 8];
            s16x8 klo = *(s16x8*)&sK[cur][16 * st + lc][((4 + g) ^ sw) * 8];
            f32x4 dd = __builtin_amdgcn_mfma_f32_16x16x32_bf16(klo, qh, z, 0, 0, 0);
            dd = __builtin_amdgcn_mfma_f32_16x16x32_bf16(kh, ql, dd, 0, 0, 0);
            dd = __builtin_amdgcn_mfma_f32_16x16x32_bf16(kh, qh, dd, 0, 0, 0);
            d[st] = dd;  // C[key=16st+4g+r][query=lc]
        }
        s16x8 va0 = *(s16x8*)&sV[cur][lc][(g ^ sw) * 8];
        s16x8 va1 = *(s16x8*)&sV[cur][lc][((4 + g) ^ sw) * 8];
        s16x8 va2 = *(s16x8*)&sV[cur][lc + 16][(g ^ sw) * 8];
        s16x8 va3 = *(s16x8*)&sV[cur][lc + 16][((4 + g) ^ sw) * 8];

        // ---- scores: sc = min(d, d + (d^2 - qn2*kn2)) (pre-CSC log2 domain) ----
        float sc[4][4];
#pragma unroll
        for (int st = 0; st < 4; st++)
#pragma unroll
            for (int r = 0; r < 4; r++) {
                float dd = d[st][r];
                float c = qn2 * kn2v[st][r];
                sc[st][r] = fminf(dd, fmaf(dd, dd, -c) + dd);
            }

        // ---- online softmax ----
        float x0 = fmaxf(fmaxf(sc[0][0], sc[0][1]), fmaxf(sc[0][2], sc[0][3]));
        float x1 = fmaxf(fmaxf(sc[1][0], sc[1][1]), fmaxf(sc[1][2], sc[1][3]));
        float x2 = fmaxf(fmaxf(sc[2][0], sc[2][1]), fmaxf(sc[2][2], sc[2][3]));
        float x3 = fmaxf(fmaxf(sc[3][0], sc[3][1]), fmaxf(sc[3][2], sc[3][3]));
        float tm = fmaxf(fmaxf(x0, x1), fmaxf(x2, x3));
        tm = fmaxf(tm, __shfl_xor(tm, 16));
        tm = fmaxf(tm, __shfl_xor(tm, 32));
        const float nm = fmaxf(m, tm);
        const float negmC = -nm * CSC;
        const float al = __builtin_amdgcn_exp2f(fmaf(m, CSC, negmC));
        m = nm;
        float p[4][4];
#pragma unroll
        for (int st = 0; st < 4; st++)
#pragma unroll
            for (int r = 0; r < 4; r++)
                p[st][r] = __builtin_amdgcn_exp2f(fmaf(sc[st][r], CSC, negmC));

        // ---- P^T -> per-wave LDS round-trip ----
#pragma unroll
        for (int st = 0; st < 4; st++) {
            const int off = (((2 * st + (g >> 1)) ^ sw) << 3) + ((g & 1) << 2);
            *(uint2*)&sP[wave][lc][off] =
                make_uint2(pk2(p[st][0], p[st][1]), pk2(p[st][2], p[st][3]));
        }
        __builtin_amdgcn_s_waitcnt(0xC07F);  // lgkmcnt(0)
        s16x8 pb0 = *(s16x8*)&sP[wave][lc][(g ^ sw) * 8];
        s16x8 pb1 = *(s16x8*)&sP[wave][lc][((4 + g) ^ sw) * 8];

        // ---- rescale + PV + l via ones-MFMA ----
        acc0 *= al;
        acc1 *= al;
        acc0 = __builtin_amdgcn_mfma_f32_16x16x32_bf16(va0, pb0, acc0, 0, 0, 0);
        acc0 = __builtin_amdgcn_mfma_f32_16x16x32_bf16(va1, pb1, acc0, 0, 0, 0);
        acc1 = __builtin_amdgcn_mfma_f32_16x16x32_bf16(va2, pb0, acc1, 0, 0, 0);
        acc1 = __builtin_amdgcn_mfma_f32_16x16x32_bf16(va3, pb1, acc1, 0, 0, 0);
        f32x4 lt = __builtin_amdgcn_mfma_f32_16x16x32_bf16(ones, pb0, z, 0, 0, 0);
        lt = __builtin_amdgcn_mfma_f32_16x16x32_bf16(ones, pb1, lt, 0, 0, 0);
        l = fmaf(l, al, lt[0]);

        // barrier: (a) everyone done reading buf cur, (b) drains DMA t+1 (vmcnt 0)
        __syncthreads();
    }

    // ---- write fp32 partials ----
    float* pa = pacc + (((size_t)bh * 4 + strip) * NL + (qw + lc)) * 32;
    *(f32x4*)(pa + 4 * g) = acc0;
    *(f32x4*)(pa + 16 + 4 * g) = acc1;
    if (g == 0) {
        *(float2*)(pml + (((size_t)bh * 4 + strip) * NL + (qw + lc)) * 2) =
            make_float2(m, l);
    }
}

// ==== combine kernel ====
__global__ __launch_bounds__(256) void ga_combine(const float* __restrict__ pacc,
                                                  const float* __restrict__ pml,
                                                  float* __restrict__ O) {
    const int tid = blockIdx.x * 256 + threadIdx.x;
    const int dq = tid & 7, q = (tid >> 3) & 2047, bh = tid >> 14;
    const int b = bh >> 3, h = bh & 7;
    float m[4], l[4];
#pragma unroll
    for (int s = 0; s < 4; s++) {
        float2 t = *(const float2*)(pml + (((size_t)bh * 4 + s) * NL + q) * 2);
        m[s] = t.x;
        l[s] = t.y;
    }
    float mf = fmaxf(fmaxf(m[0], m[1]), fmaxf(m[2], m[3]));
    float w[4], L = 0.f;
#pragma unroll
    for (int s = 0; s < 4; s++) {
        w[s] = __builtin_amdgcn_exp2f((m[s] - mf) * CSC);
        L = fmaf(l[s], w[s], L);
    }
    const float inv = 1.f / L;
    float4 o = make_float4(0.f, 0.f, 0.f, 0.f);
#pragma unroll
    for (int s = 0; s < 4; s++) {
        const float* pa = pacc + (((size_t)bh * 4 + s) * NL + q) * 32 + dq * 4;
        float4 a = *(const float4*)pa;
        o.x = fmaf(a.x, w[s], o.x);
        o.y = fmaf(a.y, w[s], o.y);
        o.z = fmaf(a.z, w[s], o.z);
        o.w = fmaf(a.w, w[s], o.w);
    }
    o.x *= inv; o.y *= inv; o.z *= inv; o.w *= inv;
    *(float4*)(O + (((size_t)(b * NL + q)) * NH + h) * 32 + dq * 4) = o;
}

// ==== fallback: round-4 kernel (validated ~81us), used only if ws too small ====
__global__ __launch_bounds__(512, 4) void ga_fallback(
    const float* __restrict__ Q, const float* __restrict__ K,
    const float* __restrict__ V, float* __restrict__ O) {
    __shared__ union {
        struct {
            u16 Kh[2][64][32];
            u16 Kl[2][64][32];
            u16 Vt[2][32][64];
            float kn2[2][64];
        } s;
        struct { float acc[8][32][17]; float m[8][16]; float l[8][16]; } c;
    } u;
    __shared__ u16 sP[8][16][64];

    const int T = threadIdx.x;
    const int lane = T & 63, wave = T >> 6;
    const int g = lane >> 4, lc = lane & 15, g8 = g * 8;
    const int half = wave >> 2;
    const int qt = blockIdx.x & 31;
    const int bh = blockIdx.x >> 5;
    const int b = bh >> 3, h = bh & 7;
    const int qw = qt * 64 + (wave & 3) * 16;

    const float* qrow = Q + ((size_t)((b * NL + qw + lc) * NH + h)) * 32 + g8;
    float4 qa = *(const float4*)qrow, qb = *(const float4*)(qrow + 4);
    float q8[8] = {qa.x, qa.y, qa.z, qa.w, qb.x, qb.y, qb.z, qb.w};
    union { unsigned u4[4]; s16x8 v; } qh_, ql_;
    float qn2 = 0.f;
#pragma unroll
    for (int i = 0; i < 4; i++) {
        float x0 = q8[2 * i], x1 = q8[2 * i + 1];
        qn2 = fmaf(x0, x0, qn2);
        qn2 = fmaf(x1, x1, qn2);
        unsigned h01 = pk2(x0, x1);
        qh_.u4[i] = h01;
        float h0 = __uint_as_float(h01 << 16);
        float h1 = __uint_as_float(h01 & 0xffff0000u);
        ql_.u4[i] = pk2(x0 - h0, x1 - h1);
    }
    const s16x8 qh = qh_.v, ql = ql_.v;
    qn2 += __shfl_xor(qn2, 16);
    qn2 += __shfl_xor(qn2, 32);

    const int Tl = T & 255;
    const int sk = Tl >> 2, kc = Tl & 3;
    const int dv = Tl & 31, vc = Tl >> 5;
    const float* kbase = K + ((size_t)(b * NS * NH) + h) * 32;
    const float* vbase = V + ((size_t)(b * NS * NH) + h) * 32;
    const int kphys = (kc ^ swzK(sk)) * 8;
    const int vphys = (vc ^ swzV(dv)) * 8;

    int s0 = half * 1024;
    float4 ka = *(const float4*)(kbase + (size_t)(s0 + sk) * 256 + kc * 8);
    float4 kb = *(const float4*)(kbase + (size_t)(s0 + sk) * 256 + kc * 8 + 4);
    float vr[8];
#pragma unroll
    for (int i = 0; i < 8; i++) vr[i] = vbase[(size_t)(s0 + 8 * vc + i) * 256 + dv];

    f32x4 acc0 = {0.f, 0.f, 0.f, 0.f}, acc1 = {0.f, 0.f, 0.f, 0.f};
    float m = -INFINITY, l = 0.f;

    for (int t = 0; t < 16; ++t) {
        {
            float kx[8] = {ka.x, ka.y, ka.z, ka.w, kb.x, kb.y, kb.z, kb.w};
            unsigned hh[4], ll[4];
            float kn2p = 0.f;
#pragma unroll
            for (int i = 0; i < 4; i++) {
                float x0 = kx[2 * i], x1 = kx[2 * i + 1];
                kn2p = fmaf(x0, x0, kn2p);
                kn2p = fmaf(x1, x1, kn2p);
                unsigned h01 = pk2(x0, x1);
                hh[i] = h01;
                float h0 = __uint_as_float(h01 << 16);
                float h1 = __uint_as_float(h01 & 0xffff0000u);
                ll[i] = pk2(x0 - h0, x1 - h1);
            }
            *(uint4*)&u.s.Kh[half][sk][kphys] = make_uint4(hh[0], hh[1], hh[2], hh[3]);
            *(uint4*)&u.s.Kl[half][sk][kphys] = make_uint4(ll[0], ll[1], ll[2], ll[3]);
            kn2p = dpp_add<0xB1>(kn2p);
            kn2p = dpp_add<0x4E>(kn2p);
            if (kc == 0) u.s.kn2[half][sk] = kn2p;
            *(uint4*)&u.s.Vt[half][dv][vphys] =
                make_uint4(pk2(vr[0], vr[1]), pk2(vr[2], vr[3]),
                           pk2(vr[4], vr[5]), pk2(vr[6], vr[7]));
        }
        const int tn = (t + 1 < 16) ? t + 1 : t;
        const int sn = half * 1024 + tn * 64;
        ka = *(const float4*)(kbase + (size_t)(sn + sk) * 256 + kc * 8);
        kb = *(const float4*)(kbase + (size_t)(sn + sk) * 256 + kc * 8 + 4);
#pragma unroll
        for (int i = 0; i < 8; i++) vr[i] = vbase[(size_t)(sn + 8 * vc + i) * 256 + dv];

        __syncthreads();

        f32x4 d[4], kn2v[4];
        const f32x4 z = {0.f, 0.f, 0.f, 0.f};
        const int skr = swzK(lc);
#pragma unroll
        for (int st = 0; st < 4; st++) {
            kn2v[st] = *(f32x4*)&u.s.kn2[half][16 * st + 4 * g];
            s16x8 kh = *(s16x8*)&u.s.Kh[half][16 * st + lc][(g ^ skr) * 8];
            s16x8 kl = *(s16x8*)&u.s.Kl[half][16 * st + lc][(g ^ skr) * 8];
            f32x4 dd = __builtin_amdgcn_mfma_f32_16x16x32_bf16(kl, qh, z, 0, 0, 0);
            dd = __builtin_amdgcn_mfma_f32_16x16x32_bf16(kh, ql, dd, 0, 0, 0);
            dd = __builtin_amdgcn_mfma_f32_16x16x32_bf16(kh, qh, dd, 0, 0, 0);
            d[st] = dd;
        }

        float sc[4][4];
#pragma unroll
        for (int st = 0; st < 4; st++)
#pragma unroll
            for (int r = 0; r < 4; r++) {
                float dd = d[st][r];
                float w = fmaxf(fmaf(-dd, dd, qn2 * kn2v[st][r]), 0.f);
                sc[st][r] = (dd - w) * CSC;
            }

        float x0 = fmaxf(fmaxf(sc[0][0], sc[0][1]), fmaxf(sc[0][2], sc[0][3]));
        float x1 = fmaxf(fmaxf(sc[1][0], sc[1][1]), fmaxf(sc[1][2], sc[1][3]));
        float x2 = fmaxf(fmaxf(sc[2][0], sc[2][1]), fmaxf(sc[2][2], sc[2][3]));
        float x3 = fmaxf(fmaxf(sc[3][0], sc[3][1]), fmaxf(sc[3][2], sc[3][3]));
        float tm = fmaxf(fmaxf(x0, x1), fmaxf(x2, x3));
        tm = fmaxf(tm, __shfl_xor(tm, 16));
        tm = fmaxf(tm, __shfl_xor(tm, 32));
        const float nm = fmaxf(m, tm);
        const float al = __builtin_amdgcn_exp2f(m - nm);
        m = nm;
        float p[4][4], ls = 0.f;
#pragma unroll
        for (int st = 0; st < 4; st++)
#pragma unroll
            for (int r = 0; r < 4; r++) {
                p[st][r] = __builtin_amdgcn_exp2f(sc[st][r] - nm);
                ls += p[st][r];
            }
        l = fmaf(l, al, ls);
        acc0 *= al;
        acc1 *= al;

#pragma unroll
        for (int st = 0; st < 4; st++) {
            const int off = ((2 * st + (g >> 1)) ^ (lc & 7)) * 8 + (g & 1) * 4;
            *(uint2*)&sP[wave][lc][off] =
                make_uint2(pk2(p[st][0], p[st][1]), pk2(p[st][2], p[st][3]));
        }
        __builtin_amdgcn_s_waitcnt(0xC07F);

        const int svl = swzV(lc), svh = swzV(lc + 16), spl = lc & 7;
        s16x8 va00 = *(s16x8*)&u.s.Vt[half][lc][(g ^ svl) * 8];
        s16x8 va01 = *(s16x8*)&u.s.Vt[half][lc][((4 + g) ^ svl) * 8];
        s16x8 va10 = *(s16x8*)&u.s.Vt[half][lc + 16][(g ^ svh) * 8];
        s16x8 va11 = *(s16x8*)&u.s.Vt[half][lc + 16][((4 + g) ^ svh) * 8];
        s16x8 pb0 = *(s16x8*)&sP[wave][lc][(g ^ spl) * 8];
        s16x8 pb1 = *(s16x8*)&sP[wave][lc][((4 + g) ^ spl) * 8];
        acc0 = __builtin_amdgcn_mfma_f32_16x16x32_bf16(va00, pb0, acc0, 0, 0, 0);
        acc0 = __builtin_amdgcn_mfma_f32_16x16x32_bf16(va01, pb1, acc0, 0, 0, 0);
        acc1 = __builtin_amdgcn_mfma_f32_16x16x32_bf16(va10, pb0, acc1, 0, 0, 0);
        acc1 = __builtin_amdgcn_mfma_f32_16x16x32_bf16(va11, pb1, acc1, 0, 0, 0);

        __syncthreads();
    }

    l += __shfl_xor(l, 16);
    l += __shfl_xor(l, 32);
#pragma unroll
    for (int r = 0; r < 4; r++) {
        u.c.acc[wave][4 * g + r][lc] = acc0[r];
        u.c.acc[wave][16 + 4 * g + r][lc] = acc1[r];
    }
    if (lane < 16) {
        u.c.m[wave][lc] = m;
        u.c.l[wave][lc] = l;
    }
    __syncthreads();

    const int q = T >> 3, dq = (T & 7) * 4, qr = q & 15;
    const int w0 = q >> 4, w1 = w0 + 4;
    float m0 = u.c.m[w0][qr], m1 = u.c.m[w1][qr];
    float l0 = u.c.l[w0][qr], l1 = u.c.l[w1][qr];
    float mf = fmaxf(m0, m1);
    float e0 = __builtin_amdgcn_exp2f(m0 - mf);
    float e1 = __builtin_amdgcn_exp2f(m1 - mf);
    float inv = 1.f / fmaf(l1, e1, l0 * e0);
    e0 *= inv;
    e1 *= inv;
    float4 o;
    o.x = u.c.acc[w0][dq + 0][qr] * e0 + u.c.acc[w1][dq + 0][qr] * e1;
    o.y = u.c.acc[w0][dq + 1][qr] * e0 + u.c.acc[w1][dq + 1][qr] * e1;
    o.z = u.c.acc[w0][dq + 2][qr] * e0 + u.c.acc[w1][dq + 2][qr] * e1;
    o.w = u.c.acc[w0][dq + 3][qr] * e0 + u.c.acc[w1][dq + 3][qr] * e1;
    *(float4*)(O + ((size_t)((b * NL + qt * 64 + q) * NH + h)) * 32 + dq) = o;
}

extern "C" void kernel_launch(void* const* d_in, const int* in_sizes, int n_in,
                              void* d_out, int out_size, void* d_ws, size_t ws_size,
                              hipStream_t stream) {
    const float* Q = (const float*)d_in[0];
    const float* K = (const float*)d_in[1];
    const float* V = (const float*)d_in[2];
    float* O = (float*)d_out;

    if (ws_size >= (size_t)WS_NEED) {
        float* kn2w = (float*)((char*)d_ws + WS_KN2_OFF);
        u16* khkl = (u16*)((char*)d_ws + WS_KHKL_OFF);
        u16* vtw = (u16*)((char*)d_ws + WS_VT_OFF);
        float* pacc = (float*)((char*)d_ws + WS_PACC_OFF);
        float* pml = (float*)((char*)d_ws + WS_PML_OFF);
        ga_pre<<<NBH * 32, 256, 0, stream>>>(K, V, kn2w, khkl, vtw);
        ga_dma<<<NBH * 32 * 4, 256, 0, stream>>>(Q, kn2w, khkl, vtw, pacc, pml);
        ga_combine<<<(NBH * NL * 8) / 256, 256, 0, stream>>>(pacc, pml, O);
    } else {
        ga_fallback<<<NBH * 32, 512, 0, stream>>>(Q, K, V, O);
    }
}